// Round 1
// 522.545 us; speedup vs baseline: 1.0381x; 1.0381x over previous
//
#include <hip/hip_runtime.h>
#include <hip/hip_bf16.h>
#include <math.h>

#define BB 2
#define NCAM 6
#define NQ 900
#define NC 256
#define BN (BB*NCAM)        // 12
#define NROW (BB*NQ)        // 1800
#define RPB 2               // rows (queries) per block

#define HW0 22400
#define HW1 5600
#define HW2 1400
#define HW3 350

typedef float f4 __attribute__((ext_vector_type(4)));
typedef unsigned short u16x4 __attribute__((ext_vector_type(4)));

__device__ __forceinline__ float u2f(unsigned short u){
  union{unsigned int v; float fl;} x; x.v=((unsigned int)u)<<16; return x.fl;
}

template<int F>
__device__ __forceinline__ float ld1(const void* p, long i){
  if (F) return u2f(((const unsigned short*)p)[i]);
  return ((const float*)p)[i];
}
template<int F>
__device__ __forceinline__ f4 ld4(const void* p, long i){ // i = element index, %4==0
  if (F){
    u16x4 u = *(const u16x4*)((const unsigned short*)p + i);
    f4 r; r.x=u2f(u.x); r.y=u2f(u.y); r.z=u2f(u.z); r.w=u2f(u.w); return r;
  }
  return *(const f4*)((const float*)p + i);
}

__device__ __forceinline__ int sniff_flag(const unsigned char* refraw){
  int cnt=0;
  for (int i=1;i<64;i+=4){
    unsigned char b = refraw[i];
    if (b>=0x30 && b<0x40) cnt++;
  }
  return (cnt>=12) ? 1 : 0;
}

// ---------------- combined prep kernel ----------------
// roles by blockIdx:
//   [0, nW)             : weight relayout  W[t][k] -> blk[k/4][t][4] fp32
//   [nW, nW+nT2)        : level-2 transpose [BN,C,HW2] -> [BN,HW2,C] fp32
//   [nW+nT2, +nT3)      : level-3 transpose [BN,C,HW3] -> [BN,HW3,C] fp32
//   last block          : dtype flag + mask normalize + extrinsic inverse
__global__ __launch_bounds__(256) void prep_all(
    const unsigned char* __restrict__ refraw,
    const void* __restrict__ ext,
    const unsigned char* __restrict__ mask_raw,
    const void* __restrict__ Wq, const void* __restrict__ Wv,
    const void* __restrict__ Wo,
    const void* __restrict__ f2, const void* __restrict__ f3,
    int nW, int nT2, int nT3,
    int* __restrict__ flag_out, float* __restrict__ inv_out,
    int* __restrict__ mask_out,
    float* __restrict__ Wblk, float* __restrict__ T2buf,
    float* __restrict__ T3buf){
  __shared__ int sflag, s_na, s_gt, s_bf;
  int t = threadIdx.x;
  int bi = blockIdx.x;
  if (t==0){ sflag = sniff_flag(refraw); s_na=0; s_gt=0; s_bf=0; }
  __syncthreads();
  int f = sflag;

  if (bi < nW){
    int e = bi*256 + t;                 // 0 .. 3*65536-1
    int mat = e >> 16;
    int i = e & 65535;
    int tt = i >> 8, k = i & 255;
    const void* W = (mat==0)?Wq:((mat==1)?Wv:Wo);
    float v = f ? u2f(((const unsigned short*)W)[i]) : ((const float*)W)[i];
    Wblk[mat*65536 + (k>>2)*1024 + tt*4 + (k&3)] = v;
    return;
  }
  if (bi < nW+nT2){
    int e = (bi-nW)*256 + t;            // < 12*1400*256
    int bn = e / (HW2*NC);
    int rem = e - bn*(HW2*NC);
    int p = rem >> 8, c = rem & 255;
    int src = (bn*NC + c)*HW2 + p;
    T2buf[e] = f ? u2f(((const unsigned short*)f2)[src]) : ((const float*)f2)[src];
    return;
  }
  if (bi < nW+nT2+nT3){
    int e = (bi-nW-nT2)*256 + t;        // < 12*350*256
    int bn = e / (HW3*NC);
    int rem = e - bn*(HW3*NC);
    int p = rem >> 8, c = rem & 255;
    int src = (bn*NC + c)*HW3 + p;
    T3buf[e] = f ? u2f(((const unsigned short*)f3)[src]) : ((const float*)f3)[src];
    return;
  }

  // ---- prep block ----
  int f_na=0, f_gt=0, f_bf=0;
  for (int i=t;i<NROW;i+=blockDim.x){
    unsigned char b = mask_raw[i];
    if ((i&3)!=0 && b!=0) f_na=1;
    if (b>1) f_gt=1;
    if ((i&3)==1 && b==0x3f) f_bf=1;
  }
  if (f_na) atomicOr(&s_na,1);
  if (f_gt) atomicOr(&s_gt,1);
  if (f_bf) atomicOr(&s_bf,1);
  __syncthreads();
  int fmt; // 0=int32, 1=uint8(bool), 2=bf16, 3=fp32
  if (!s_na) fmt=0;
  else if (!s_gt) fmt=1;
  else fmt = s_bf ? 2 : 3;
  for (int i=t;i<NROW;i+=blockDim.x){
    int v;
    if (fmt==0)      v = (((const int*)mask_raw)[i]            != 0);
    else if (fmt==1) v = (mask_raw[i]                          != 0);
    else if (fmt==2) v = (((const unsigned short*)mask_raw)[i] != 0);
    else             v = (((const float*)mask_raw)[i]          != 0.0f);
    mask_out[i]=v;
  }
  if (t==0) *flag_out = f;
  if (t < BN){
    double a[4][8];
    for(int i=0;i<4;i++){
      for(int j=0;j<4;j++) a[i][j] = (double)(f? u2f(((const unsigned short*)ext)[t*16+i*4+j])
                                               : ((const float*)ext)[t*16+i*4+j]);
      for(int j=0;j<4;j++) a[i][4+j] = (i==j)?1.0:0.0;
    }
    for(int col=0;col<4;col++){
      int piv=col; double best=fabs(a[col][col]);
      for(int r=col+1;r<4;r++){ double v=fabs(a[r][col]); if(v>best){best=v;piv=r;} }
      if(piv!=col) for(int j=0;j<8;j++){ double tmp=a[col][j]; a[col][j]=a[piv][j]; a[piv][j]=tmp; }
      double id = 1.0/a[col][col];
      for(int j=0;j<8;j++) a[col][j]*=id;
      for(int r=0;r<4;r++) if(r!=col){
        double fc=a[r][col];
        for(int j=0;j<8;j++) a[r][j]-=fc*a[col][j];
      }
    }
    for(int i=0;i<4;i++)for(int j=0;j<4;j++){
      float v=(float)a[i][4+j];
      if (isnan(v)) v=0.f;
      else if (isinf(v)) v = (v>0.f)?1e6f:-1e6f;
      inv_out[t*16+i*4+j]=v;
    }
  }
}

// ---------------- fused kernel, RPB rows per block ----------------
struct SharedMem {
  float q[RPB][NC];
  float ms[RPB][NCAM][NC];
  float fus[RPB][NC];
  float px[RPB][NCAM], py[RPB][NCAM];
  int   iv[RPB][NCAM];
  int   off[RPB][NCAM*4][4];
  float wgt[RPB][NCAM*4][4];
};

// RL: weights from relaid fp32 blocked buffer. RF: 0 none, 1 l3 relaid, 2 l2+l3 relaid.
template<int F, int RL, int RF>
__device__ __forceinline__ void fused_body(
    const void* __restrict__ query, const void* __restrict__ refpts,
    const void* __restrict__ intr,
    const void* __restrict__ f0, const void* __restrict__ f1,
    const void* __restrict__ f2, const void* __restrict__ f3,
    const void* __restrict__ Wq, const void* __restrict__ bq,
    const void* __restrict__ Wv, const void* __restrict__ bv,
    const void* __restrict__ Wo, const void* __restrict__ bo,
    const float* __restrict__ Wblk,
    const float* __restrict__ T2buf, const float* __restrict__ T3buf,
    const float* __restrict__ inv_ext, const int* __restrict__ mask_int,
    float* __restrict__ out, SharedMem& sm){
  int r0 = blockIdx.x*RPB;
  int t = threadIdx.x;

  const f4* Wq4 = (const f4*)(Wblk);
  const f4* Wv4 = (const f4*)(Wblk + 65536);
  const f4* Wo4 = (const f4*)(Wblk + 131072);

  // phase 1: stage query rows; first RPB*NCAM threads project through cameras
  #pragma unroll
  for(int i=0;i<RPB;i++) sm.q[i][t] = ld1<F>(query,(long)(r0+i)*NC+t);

  if (t < RPB*NCAM){
    int i = t/NCAM, n = t - i*NCAM;
    int row = r0+i, b = row/NQ;
    int m = mask_int[row];
    float h0 = ld1<F>(refpts,(long)row*3+0)*102.4f - 51.2f;
    float h1 = ld1<F>(refpts,(long)row*3+1)*102.4f - 51.2f;
    float h2 = ld1<F>(refpts,(long)row*3+2)*102.4f - 51.2f;
    if (m){ h0=-1000.f; h1=-1000.f; h2=-1000.f; }
    const float* M = inv_ext + (b*NCAM+n)*16;
    float c0 = M[0]*h0 + M[1]*h1 + M[2]*h2 + M[3];
    float c1 = M[4]*h0 + M[5]*h1 + M[6]*h2 + M[7];
    float c2 = M[8]*h0 + M[9]*h1 + M[10]*h2 + M[11];
    float depth = c2;
    if (isnan(depth)) depth = 10.f;
    else if (isinf(depth)) depth = (depth>0)?100.f:-100.f;
    int iv = (depth < 1.5f);
    float ds = fmaxf(depth, 1.5f);
    float pc0=c0/ds, pc1=c1/ds, pc2=c2/ds;
    long kb = (long)(b*NCAM+n)*9;
    float ix = ld1<F>(intr,kb+0)*pc0 + ld1<F>(intr,kb+1)*pc1 + ld1<F>(intr,kb+2)*pc2;
    float iy = ld1<F>(intr,kb+3)*pc0 + ld1<F>(intr,kb+4)*pc1 + ld1<F>(intr,kb+5)*pc2;
    sm.px[i][n] = fminf(fmaxf(ix,-3000.f),3000.f);
    sm.py[i][n] = fminf(fmaxf(iy,-3000.f),3000.f);
    sm.iv[i][n] = iv;
  }
  __syncthreads();

  // phase 2: per (row,cam,level) corner offsets + weights
  if (t < RPB*NCAM*4){
    const int Ws_[4]={200,100,50,25}, Hs_[4]={112,56,28,14};
    int i = t/(NCAM*4), u = t - i*(NCAM*4);
    int n = u>>2, l = u&3;
    float x=sm.px[i][n], y=sm.py[i][n];
    int iv=sm.iv[i][n];
    int W=Ws_[l], H=Hs_[l];
    float gx = (x * ((float)W/800.f)) / (W-1.f) * 2.f - 1.f;
    float gy = (y * ((float)H/448.f)) / (H-1.f) * 2.f - 1.f;
    gx=fminf(fmaxf(gx,-10.f),10.f); gy=fminf(fmaxf(gy,-10.f),10.f);
    if(iv){gx=-100.f;gy=-100.f;}
    float pxx=(gx+1.f)*0.5f*(W-1.f);
    float pyy=(gy+1.f)*0.5f*(H-1.f);
    float x0f=floorf(pxx), y0f=floorf(pyy);
    int x0=(int)x0f, y0=(int)y0f;
    float wx1=pxx-x0f, wy1=pyy-y0f, wx0=1.f-wx1, wy0=1.f-wy1;
    int vx0=(x0>=0)&(x0<W), vx1=(x0+1>=0)&(x0+1<W);
    int vy0=(y0>=0)&(y0<H), vy1=(y0+1>=0)&(y0+1<H);
    int cx0=min(max(x0,0),W-1), cx1=min(max(x0+1,0),W-1);
    int cy0=min(max(y0,0),H-1), cy1=min(max(y0+1,0),H-1);
    sm.off[i][u][0]=cy0*W+cx0; sm.wgt[i][u][0]=wx0*wy0*(float)(vx0&vy0);
    sm.off[i][u][1]=cy0*W+cx1; sm.wgt[i][u][1]=wx1*wy0*(float)(vx1&vy0);
    sm.off[i][u][2]=cy1*W+cx0; sm.wgt[i][u][2]=wx0*wy1*(float)(vx0&vy1);
    sm.off[i][u][3]=cy1*W+cx1; sm.wgt[i][u][3]=wx1*wy1*(float)(vx1&vy1);
  }
  __syncthreads();

  // phase 3: sampling. thread t = channel t. Loads batched into regs first (MLP).
  #pragma unroll
  for(int i=0;i<RPB;i++){
    int b = (r0+i)/NQ;
    #pragma unroll
    for(int n=0;n<NCAM;n++){
      int bn = b*NCAM+n;
      int chan = bn*NC + t;
      float v[16];
      { // levels 0,1: gathered from original [C,H,W] layout
        long cb0 = (long)chan*HW0;
        #pragma unroll
        for(int c=0;c<4;c++) v[c]   = ld1<F>(f0, cb0 + sm.off[i][n*4+0][c]);
        long cb1 = (long)chan*HW1;
        #pragma unroll
        for(int c=0;c<4;c++) v[4+c] = ld1<F>(f1, cb1 + sm.off[i][n*4+1][c]);
      }
      if (RF>=2){ // level 2 channel-last: coalesced across threads
        const float* Tp = T2buf + bn*(HW2*NC) + t;
        #pragma unroll
        for(int c=0;c<4;c++) v[8+c] = Tp[sm.off[i][n*4+2][c]*NC];
      } else {
        long cb2 = (long)chan*HW2;
        #pragma unroll
        for(int c=0;c<4;c++) v[8+c] = ld1<F>(f2, cb2 + sm.off[i][n*4+2][c]);
      }
      if (RF>=1){ // level 3 channel-last
        const float* Tp = T3buf + bn*(HW3*NC) + t;
        #pragma unroll
        for(int c=0;c<4;c++) v[12+c] = Tp[sm.off[i][n*4+3][c]*NC];
      } else {
        long cb3 = (long)chan*HW3;
        #pragma unroll
        for(int c=0;c<4;c++) v[12+c] = ld1<F>(f3, cb3 + sm.off[i][n*4+3][c]);
      }
      float acc=0.f;
      #pragma unroll
      for(int l=0;l<4;l++){
        #pragma unroll
        for(int c=0;c<4;c++)
          acc = fmaf(sm.wgt[i][n*4+l][c], v[l*4+c], acc);
      }
      sm.ms[i][n][t] = acc*0.25f;
    }
  }

  // phase 4: q projection (row t of Wq), weight loaded once for RPB rows
  float qv[RPB];
  #pragma unroll
  for(int i=0;i<RPB;i++) qv[i]=0.f;
  {
    #pragma unroll 8
    for(int k4=0;k4<NC/4;k4++){
      f4 wv = RL ? Wq4[k4*256 + t] : ld4<F>(Wq, (long)t*NC + 4*k4);
      #pragma unroll
      for(int i=0;i<RPB;i++){
        f4 xv = ((const f4*)sm.q[i])[k4];
        qv[i]=fmaf(wv.x,xv.x,qv[i]); qv[i]=fmaf(wv.y,xv.y,qv[i]);
        qv[i]=fmaf(wv.z,xv.z,qv[i]); qv[i]=fmaf(wv.w,xv.w,qv[i]);
      }
    }
    float bqv = ld1<F>(bq,t);
    #pragma unroll
    for(int i=0;i<RPB;i++) qv[i]+=bqv;
  }
  __syncthreads();   // sm.ms ready

  // phase 5: v projection + max over cameras, weight loaded once for RPB rows
  float ac[RPB][NCAM];
  #pragma unroll
  for(int i=0;i<RPB;i++)
    #pragma unroll
    for(int n=0;n<NCAM;n++) ac[i][n]=0.f;
  {
    #pragma unroll 2
    for(int k4=0;k4<NC/4;k4++){
      f4 wv = RL ? Wv4[k4*256 + t] : ld4<F>(Wv, (long)t*NC + 4*k4);
      #pragma unroll
      for(int i=0;i<RPB;i++){
        #pragma unroll
        for(int n=0;n<NCAM;n++){
          f4 mv=((const f4*)sm.ms[i][n])[k4];
          ac[i][n]=fmaf(wv.x,mv.x,ac[i][n]); ac[i][n]=fmaf(wv.y,mv.y,ac[i][n]);
          ac[i][n]=fmaf(wv.z,mv.z,ac[i][n]); ac[i][n]=fmaf(wv.w,mv.w,ac[i][n]);
        }
      }
    }
  }
  {
    float bvv = ld1<F>(bv,t);
    #pragma unroll
    for(int i=0;i<RPB;i++){
      float sv = ac[i][0];
      #pragma unroll
      for(int n=1;n<NCAM;n++) sv = fmaxf(sv, ac[i][n]);
      sv += bvv;
      sm.fus[i][t] = fmaxf(qv[i]+sv, 0.f) + qv[i];
    }
  }
  __syncthreads();

  // phase 6: output projection
  float o[RPB];
  #pragma unroll
  for(int i=0;i<RPB;i++) o[i]=0.f;
  {
    #pragma unroll 8
    for(int k4=0;k4<NC/4;k4++){
      f4 wv = RL ? Wo4[k4*256 + t] : ld4<F>(Wo, (long)t*NC + 4*k4);
      #pragma unroll
      for(int i=0;i<RPB;i++){
        f4 xv = ((const f4*)sm.fus[i])[k4];
        o[i]=fmaf(wv.x,xv.x,o[i]); o[i]=fmaf(wv.y,xv.y,o[i]);
        o[i]=fmaf(wv.z,xv.z,o[i]); o[i]=fmaf(wv.w,xv.w,o[i]);
      }
    }
    float bov = ld1<F>(bo,t);
    #pragma unroll
    for(int i=0;i<RPB;i++){
      int m = mask_int[r0+i];
      float r = o[i] + bov;
      if (m) r = 0.f;
      out[(long)(r0+i)*NC+t] = r;
    }
  }
}

template<int RL, int RF>
__global__ __launch_bounds__(256,4) void fused_kernel(
    const void* query, const void* refpts, const void* intr,
    const void* f0, const void* f1, const void* f2, const void* f3,
    const void* Wq, const void* bq, const void* Wv, const void* bv,
    const void* Wo, const void* bo, const float* __restrict__ Wblk,
    const float* __restrict__ T2buf, const float* __restrict__ T3buf,
    const float* __restrict__ inv_ext, const int* __restrict__ mask_int,
    const int* __restrict__ flag, float* __restrict__ out){
  __shared__ SharedMem sm;
  if (*flag)
    fused_body<1,RL,RF>(query,refpts,intr,f0,f1,f2,f3,Wq,bq,Wv,bv,Wo,bo,
                        Wblk,T2buf,T3buf,inv_ext,mask_int,out,sm);
  else
    fused_body<0,RL,RF>(query,refpts,intr,f0,f1,f2,f3,Wq,bq,Wv,bv,Wo,bo,
                        Wblk,T2buf,T3buf,inv_ext,mask_int,out,sm);
}

extern "C" void kernel_launch(void* const* d_in, const int* in_sizes, int n_in,
                              void* d_out, int out_size, void* d_ws, size_t ws_size,
                              hipStream_t stream){
  const void* query  = d_in[0];
  const void* refpts = d_in[1];
  const unsigned char* mask_raw = (const unsigned char*)d_in[2];
  const void* intr   = d_in[3];
  const void* ext    = d_in[4];
  const void* f0     = d_in[5];
  const void* f1     = d_in[6];
  const void* f2     = d_in[7];
  const void* f3     = d_in[8];
  const void* Wq     = d_in[9];
  const void* bq     = d_in[10];
  const void* Wv     = d_in[11];
  const void* bv     = d_in[12];
  const void* Wo     = d_in[13];
  const void* bo     = d_in[14];

  char* ws = (char*)d_ws;
  float* inv_ext  = (float*)(ws + 0);         // 768 B
  int*   dflag    = (int*)  (ws + 1024);      // 4 B
  int*   mask_int = (int*)  (ws + 2048);      // 7200 B
  float* Wblk     = (float*)(ws + 16384);     // 786432 B
  float* T3buf    = (float*)(ws + 802816);    // 12*350*256*4  = 4300800 B
  float* T2buf    = (float*)(ws + 5103616);   // 12*1400*256*4 = 17203200 B
                                              // end: 22306816 B

  const size_t needW  = 802816;
  const size_t need3  = 5103616;
  const size_t need23 = 22306816;

  int rl = (ws_size >= needW) ? 1 : 0;
  int rf = (ws_size >= need23) ? 2 : ((ws_size >= need3) ? 1 : 0);

  int nW  = rl ? 768 : 0;
  int nT2 = (rf>=2) ? (BN*HW2*NC)/256 : 0;   // 16800
  int nT3 = (rf>=1) ? (BN*HW3*NC)/256 : 0;   // 4200

  hipLaunchKernelGGL(prep_all, dim3(nW+nT2+nT3+1), dim3(256), 0, stream,
                     (const unsigned char*)refpts, ext, mask_raw,
                     Wq, Wv, Wo, f2, f3, nW, nT2, nT3,
                     dflag, inv_ext, mask_int, Wblk, T2buf, T3buf);

  dim3 grid(NROW/RPB);
  if (rl && rf==2)
    hipLaunchKernelGGL(HIP_KERNEL_NAME(fused_kernel<1,2>), grid, dim3(256), 0, stream,
                       query, refpts, intr, f0, f1, f2, f3,
                       Wq, bq, Wv, bv, Wo, bo, Wblk, T2buf, T3buf,
                       inv_ext, mask_int, dflag, (float*)d_out);
  else if (rl && rf==1)
    hipLaunchKernelGGL(HIP_KERNEL_NAME(fused_kernel<1,1>), grid, dim3(256), 0, stream,
                       query, refpts, intr, f0, f1, f2, f3,
                       Wq, bq, Wv, bv, Wo, bo, Wblk, T2buf, T3buf,
                       inv_ext, mask_int, dflag, (float*)d_out);
  else if (rl)
    hipLaunchKernelGGL(HIP_KERNEL_NAME(fused_kernel<1,0>), grid, dim3(256), 0, stream,
                       query, refpts, intr, f0, f1, f2, f3,
                       Wq, bq, Wv, bv, Wo, bo, Wblk, T2buf, T3buf,
                       inv_ext, mask_int, dflag, (float*)d_out);
  else
    hipLaunchKernelGGL(HIP_KERNEL_NAME(fused_kernel<0,0>), grid, dim3(256), 0, stream,
                       query, refpts, intr, f0, f1, f2, f3,
                       Wq, bq, Wv, bv, Wo, bo, Wblk, T2buf, T3buf,
                       inv_ext, mask_int, dflag, (float*)d_out);
}

// Round 2
// 503.272 us; speedup vs baseline: 1.0779x; 1.0383x over previous
//
#include <hip/hip_runtime.h>
#include <hip/hip_bf16.h>
#include <math.h>

#define BB 2
#define NCAM 6
#define NQ 900
#define NC 256
#define BN (BB*NCAM)        // 12
#define NROW (BB*NQ)        // 1800

#define HW0 22400
#define HW1 5600
#define HW2 1400
#define HW3 350

typedef float f4 __attribute__((ext_vector_type(4)));
typedef unsigned short u16x4 __attribute__((ext_vector_type(4)));
typedef struct __attribute__((aligned(4))) { float x, y; } pf2;   // 4B-aligned float pair

__device__ __forceinline__ float u2f(unsigned short u){
  union{unsigned int v; float fl;} x; x.v=((unsigned int)u)<<16; return x.fl;
}

template<int F>
__device__ __forceinline__ float ld1(const void* p, long i){
  if (F) return u2f(((const unsigned short*)p)[i]);
  return ((const float*)p)[i];
}
template<int F>
__device__ __forceinline__ f4 ld4(const void* p, long i){ // i = element index, %4==0
  if (F){
    u16x4 u = *(const u16x4*)((const unsigned short*)p + i);
    f4 r; r.x=u2f(u.x); r.y=u2f(u.y); r.z=u2f(u.z); r.w=u2f(u.w); return r;
  }
  return *(const f4*)((const float*)p + i);
}

// 4 bilinear corner values via 2 paired loads (fp32) or 4 scalar loads (bf16).
// offA/offB are row bases (cy0*W+px, cy1*W+px) with px=clamp(x0,0,W-2);
// d0/d1 in {0,1} select the clip-index within the pair.
template<int F>
__device__ __forceinline__ void corner4(const void* fp, long cb, int offA, int offB,
                                        int d0, int d1, float* v){
  if (F){
    v[0]=ld1<1>(fp,cb+offA+d0); v[1]=ld1<1>(fp,cb+offA+d1);
    v[2]=ld1<1>(fp,cb+offB+d0); v[3]=ld1<1>(fp,cb+offB+d1);
  } else {
    pf2 a = *(const pf2*)((const float*)fp + cb + offA);
    pf2 b = *(const pf2*)((const float*)fp + cb + offB);
    v[0]=d0?a.y:a.x; v[1]=d1?a.y:a.x;
    v[2]=d0?b.y:b.x; v[3]=d1?b.y:b.x;
  }
}

__device__ __forceinline__ int sniff_flag(const unsigned char* refraw){
  int cnt=0;
  for (int i=1;i<64;i+=4){
    unsigned char b = refraw[i];
    if (b>=0x30 && b<0x40) cnt++;
  }
  return (cnt>=12) ? 1 : 0;
}

// ---------------- combined prep kernel ----------------
// roles by blockIdx:
//   [0, nW)                 : weight relayout  W[t][k] -> blk[k/4][t][4] fp32
//   [nW, nW+nT2t)           : level-2 tiled transpose [BN,C,HW2] -> [BN,HW2,C] fp32
//   [nW+nT2t, +nT3t)        : level-3 tiled transpose [BN,C,HW3] -> [BN,HW3,C] fp32
//   last block              : dtype flag + mask normalize + extrinsic inverse
#define TILES2 (8*44)     // per-bn tiles for HW2=1400 (44 p-tiles x 8 c-tiles)
#define TILES3 (8*11)     // per-bn tiles for HW3=350
__global__ __launch_bounds__(256) void prep_all(
    const unsigned char* __restrict__ refraw,
    const void* __restrict__ ext,
    const unsigned char* __restrict__ mask_raw,
    const void* __restrict__ Wq, const void* __restrict__ Wv,
    const void* __restrict__ Wo,
    const void* __restrict__ f2, const void* __restrict__ f3,
    int nW, int nT2t, int nT3t,
    int* __restrict__ flag_out, float* __restrict__ inv_out,
    int* __restrict__ mask_out,
    float* __restrict__ Wblk, float* __restrict__ T2buf,
    float* __restrict__ T3buf){
  __shared__ int sflag, s_na, s_gt, s_bf;
  __shared__ float tile[32][33];
  int t = threadIdx.x;
  int bi = blockIdx.x;
  if (t==0){ sflag = sniff_flag(refraw); s_na=0; s_gt=0; s_bf=0; }
  __syncthreads();
  int f = sflag;

  if (bi < nW){
    int e = bi*256 + t;                 // 0 .. 3*65536-1
    int mat = e >> 16;
    int i = e & 65535;
    int tt = i >> 8, k = i & 255;
    const void* W = (mat==0)?Wq:((mat==1)?Wv:Wo);
    float v = f ? u2f(((const unsigned short*)W)[i]) : ((const float*)W)[i];
    Wblk[mat*65536 + (k>>2)*1024 + tt*4 + (k&3)] = v;
    return;
  }
  if (bi < nW+nT2t+nT3t){
    // LDS-tiled transpose: both global sides coalesced.
    int idx = bi - nW;
    const void* src; float* dst; int HW, tpb, tp;
    if (idx < nT2t){ HW=HW2; src=f2; dst=T2buf; tpb=TILES2; tp=44; }
    else { idx -= nT2t; HW=HW3; src=f3; dst=T3buf; tpb=TILES3; tp=11; }
    int bn = idx / tpb; int rem = idx - bn*tpb;
    int ct = rem / tp,  pt = rem - ct*tp;
    int c0 = ct*32, p0 = pt*32;
    int ty = t>>5, tx = t&31;
    #pragma unroll
    for (int r=0;r<4;r++){
      int c = c0 + ty + r*8;          // < 256 always
      int p = p0 + tx;
      float v = 0.f;
      if (p < HW){
        long s = (long)(bn*NC + c)*HW + p;
        v = f ? u2f(((const unsigned short*)src)[s]) : ((const float*)src)[s];
      }
      tile[ty+r*8][tx] = v;
    }
    __syncthreads();
    #pragma unroll
    for (int r=0;r<4;r++){
      int p = p0 + ty + r*8;
      if (p < HW)
        dst[((long)bn*HW + p)*NC + c0 + tx] = tile[tx][ty+r*8];
    }
    return;
  }

  // ---- prep block ----
  int f_na=0, f_gt=0, f_bf=0;
  for (int i=t;i<NROW;i+=blockDim.x){
    unsigned char b = mask_raw[i];
    if ((i&3)!=0 && b!=0) f_na=1;
    if (b>1) f_gt=1;
    if ((i&3)==1 && b==0x3f) f_bf=1;
  }
  if (f_na) atomicOr(&s_na,1);
  if (f_gt) atomicOr(&s_gt,1);
  if (f_bf) atomicOr(&s_bf,1);
  __syncthreads();
  int fmt; // 0=int32, 1=uint8(bool), 2=bf16, 3=fp32
  if (!s_na) fmt=0;
  else if (!s_gt) fmt=1;
  else fmt = s_bf ? 2 : 3;
  for (int i=t;i<NROW;i+=blockDim.x){
    int v;
    if (fmt==0)      v = (((const int*)mask_raw)[i]            != 0);
    else if (fmt==1) v = (mask_raw[i]                          != 0);
    else if (fmt==2) v = (((const unsigned short*)mask_raw)[i] != 0);
    else             v = (((const float*)mask_raw)[i]          != 0.0f);
    mask_out[i]=v;
  }
  if (t==0) *flag_out = f;
  if (t < BN){
    double a[4][8];
    for(int i=0;i<4;i++){
      for(int j=0;j<4;j++) a[i][j] = (double)(f? u2f(((const unsigned short*)ext)[t*16+i*4+j])
                                               : ((const float*)ext)[t*16+i*4+j]);
      for(int j=0;j<4;j++) a[i][4+j] = (i==j)?1.0:0.0;
    }
    for(int col=0;col<4;col++){
      int piv=col; double best=fabs(a[col][col]);
      for(int r=col+1;r<4;r++){ double v=fabs(a[r][col]); if(v>best){best=v;piv=r;} }
      if(piv!=col) for(int j=0;j<8;j++){ double tmp=a[col][j]; a[col][j]=a[piv][j]; a[piv][j]=tmp; }
      double id = 1.0/a[col][col];
      for(int j=0;j<8;j++) a[col][j]*=id;
      for(int r=0;r<4;r++) if(r!=col){
        double fc=a[r][col];
        for(int j=0;j<8;j++) a[r][j]-=fc*a[col][j];
      }
    }
    for(int i=0;i<4;i++)for(int j=0;j<4;j++){
      float v=(float)a[i][4+j];
      if (isnan(v)) v=0.f;
      else if (isinf(v)) v = (v>0.f)?1e6f:-1e6f;
      inv_out[t*16+i*4+j]=v;
    }
  }
}

// ---------------- fused kernel, 1 row per block ----------------
struct SharedMem {
  float q[NC];
  float ms[NCAM][NC];
  float fus[NC];
  float px[NCAM], py[NCAM];
  int   iv[NCAM];
  int   off[NCAM*4][4];   // [0]=offA (y0 row base), [1]=offB (y1 row base), [2]=d0, [3]=d1
  float wgt[NCAM*4][4];
};

// RL: weights from relaid fp32 blocked buffer. RF: 0 none, 1 l3 relaid, 2 l2+l3 relaid.
template<int F, int RL, int RF>
__device__ __forceinline__ void fused_body(
    const void* __restrict__ query, const void* __restrict__ refpts,
    const void* __restrict__ intr,
    const void* __restrict__ f0, const void* __restrict__ f1,
    const void* __restrict__ f2, const void* __restrict__ f3,
    const void* __restrict__ Wq, const void* __restrict__ bq,
    const void* __restrict__ Wv, const void* __restrict__ bv,
    const void* __restrict__ Wo, const void* __restrict__ bo,
    const float* __restrict__ Wblk,
    const float* __restrict__ T2buf, const float* __restrict__ T3buf,
    const float* __restrict__ inv_ext, const int* __restrict__ mask_int,
    float* __restrict__ out, SharedMem& sm){
  int row = blockIdx.x;
  int b = row/NQ;
  int t = threadIdx.x;
  int m = mask_int[row];

  const f4* Wq4 = (const f4*)(Wblk);
  const f4* Wv4 = (const f4*)(Wblk + 65536);
  const f4* Wo4 = (const f4*)(Wblk + 131072);

  // phase 1: stage query row; threads 0..5 project through camera t
  sm.q[t] = ld1<F>(query, (long)row*NC+t);
  if (t < NCAM){
    float h0 = ld1<F>(refpts,(long)row*3+0)*102.4f - 51.2f;
    float h1 = ld1<F>(refpts,(long)row*3+1)*102.4f - 51.2f;
    float h2 = ld1<F>(refpts,(long)row*3+2)*102.4f - 51.2f;
    if (m){ h0=-1000.f; h1=-1000.f; h2=-1000.f; }
    const float* M = inv_ext + (b*NCAM+t)*16;
    float c0 = M[0]*h0 + M[1]*h1 + M[2]*h2 + M[3];
    float c1 = M[4]*h0 + M[5]*h1 + M[6]*h2 + M[7];
    float c2 = M[8]*h0 + M[9]*h1 + M[10]*h2 + M[11];
    float depth = c2;
    if (isnan(depth)) depth = 10.f;
    else if (isinf(depth)) depth = (depth>0)?100.f:-100.f;
    int iv = (depth < 1.5f);
    float ds = fmaxf(depth, 1.5f);
    float pc0=c0/ds, pc1=c1/ds, pc2=c2/ds;
    long kb = (long)(b*NCAM+t)*9;
    float ix = ld1<F>(intr,kb+0)*pc0 + ld1<F>(intr,kb+1)*pc1 + ld1<F>(intr,kb+2)*pc2;
    float iy = ld1<F>(intr,kb+3)*pc0 + ld1<F>(intr,kb+4)*pc1 + ld1<F>(intr,kb+5)*pc2;
    sm.px[t] = fminf(fmaxf(ix,-3000.f),3000.f);
    sm.py[t] = fminf(fmaxf(iy,-3000.f),3000.f);
    sm.iv[t] = iv;
  }
  __syncthreads();

  // phase 2: threads 0..23 precompute per-(cam,level) pair bases + selects + weights
  if (t < NCAM*4){
    const int Ws_[4]={200,100,50,25}, Hs_[4]={112,56,28,14};
    int n=t>>2, l=t&3;
    float x=sm.px[n], y=sm.py[n];
    int iv=sm.iv[n];
    int W=Ws_[l], H=Hs_[l];
    float gx = (x * ((float)W/800.f)) / (W-1.f) * 2.f - 1.f;
    float gy = (y * ((float)H/448.f)) / (H-1.f) * 2.f - 1.f;
    gx=fminf(fmaxf(gx,-10.f),10.f); gy=fminf(fmaxf(gy,-10.f),10.f);
    if(iv){gx=-100.f;gy=-100.f;}
    float pxx=(gx+1.f)*0.5f*(W-1.f);
    float pyy=(gy+1.f)*0.5f*(H-1.f);
    float x0f=floorf(pxx), y0f=floorf(pyy);
    int x0=(int)x0f, y0=(int)y0f;
    float wx1=pxx-x0f, wy1=pyy-y0f, wx0=1.f-wx1, wy0=1.f-wy1;
    int vx0=(x0>=0)&(x0<W), vx1=(x0+1>=0)&(x0+1<W);
    int vy0=(y0>=0)&(y0<H), vy1=(y0+1>=0)&(y0+1<H);
    int cx0=min(max(x0,0),W-1), cx1=min(max(x0+1,0),W-1);
    int cy0=min(max(y0,0),H-1), cy1=min(max(y0+1,0),H-1);
    int px = min(max(x0,0),W-2);         // pair base column
    int d0 = cx0 - px, d1 = cx1 - px;    // in {0,1}: clip-index within pair
    sm.off[t][0]=cy0*W+px; sm.off[t][1]=cy1*W+px;
    sm.off[t][2]=d0;       sm.off[t][3]=d1;
    sm.wgt[t][0]=wx0*wy0*(float)(vx0&vy0);
    sm.wgt[t][1]=wx1*wy0*(float)(vx1&vy0);
    sm.wgt[t][2]=wx0*wy1*(float)(vx0&vy1);
    sm.wgt[t][3]=wx1*wy1*(float)(vx1&vy1);
  }
  __syncthreads();

  // phase 3: sampling — thread t = channel t; paired gathers for l0/l1,
  // coalesced channel-last loads for l2/l3 (when relaid).
  {
    const long HWs01[2]={HW0,HW1};
    const void* fb01[2]={f0,f1};
    int bnb = b*NCAM;
    #pragma unroll
    for(int n=0;n<NCAM;n++){
      int bn = bnb+n;
      int chan = bn*NC + t;
      float v[16];
      #pragma unroll
      for(int l=0;l<2;l++){
        int u=n*4+l;
        corner4<F>(fb01[l], (long)chan*HWs01[l],
                   sm.off[u][0], sm.off[u][1], sm.off[u][2], sm.off[u][3], &v[l*4]);
      }
      {
        int u=n*4+2;
        if (RF>=2){
          const float* Tp = T2buf + (long)bn*(HW2*NC) + t;
          int oA=sm.off[u][0], oB=sm.off[u][1], d0=sm.off[u][2], d1=sm.off[u][3];
          v[8] =Tp[(long)(oA+d0)*NC]; v[9] =Tp[(long)(oA+d1)*NC];
          v[10]=Tp[(long)(oB+d0)*NC]; v[11]=Tp[(long)(oB+d1)*NC];
        } else {
          corner4<F>(f2, (long)chan*HW2,
                     sm.off[u][0], sm.off[u][1], sm.off[u][2], sm.off[u][3], &v[8]);
        }
      }
      {
        int u=n*4+3;
        if (RF>=1){
          const float* Tp = T3buf + (long)bn*(HW3*NC) + t;
          int oA=sm.off[u][0], oB=sm.off[u][1], d0=sm.off[u][2], d1=sm.off[u][3];
          v[12]=Tp[(long)(oA+d0)*NC]; v[13]=Tp[(long)(oA+d1)*NC];
          v[14]=Tp[(long)(oB+d0)*NC]; v[15]=Tp[(long)(oB+d1)*NC];
        } else {
          corner4<F>(f3, (long)chan*HW3,
                     sm.off[u][0], sm.off[u][1], sm.off[u][2], sm.off[u][3], &v[12]);
        }
      }
      float acc=0.f;
      #pragma unroll
      for(int l=0;l<4;l++){
        #pragma unroll
        for(int c=0;c<4;c++)
          acc = fmaf(sm.wgt[n*4+l][c], v[l*4+c], acc);
      }
      sm.ms[n][t]=acc*0.25f;
    }
  }

  // phase 4: q projection (row t of Wq)
  float qv = 0.f;
  {
    const f4* sq4=(const f4*)sm.q;
    #pragma unroll 8
    for(int k4=0;k4<NC/4;k4++){
      f4 wv = RL ? Wq4[k4*256 + t] : ld4<F>(Wq, (long)t*NC + 4*k4);
      f4 xv = sq4[k4];
      qv=fmaf(wv.x,xv.x,qv); qv=fmaf(wv.y,xv.y,qv);
      qv=fmaf(wv.z,xv.z,qv); qv=fmaf(wv.w,xv.w,qv);
    }
    qv += ld1<F>(bq,t);
  }
  __syncthreads();   // sm.ms ready

  // phase 5: v projection + max over cameras
  float ac[NCAM];
  #pragma unroll
  for(int n=0;n<NCAM;n++) ac[n]=0.f;
  {
    #pragma unroll 4
    for(int k4=0;k4<NC/4;k4++){
      f4 wv = RL ? Wv4[k4*256 + t] : ld4<F>(Wv, (long)t*NC + 4*k4);
      #pragma unroll
      for(int n=0;n<NCAM;n++){
        f4 mv=((const f4*)sm.ms[n])[k4];
        ac[n]=fmaf(wv.x,mv.x,ac[n]); ac[n]=fmaf(wv.y,mv.y,ac[n]);
        ac[n]=fmaf(wv.z,mv.z,ac[n]); ac[n]=fmaf(wv.w,mv.w,ac[n]);
      }
    }
  }
  float sv = ac[0];
  #pragma unroll
  for(int n=1;n<NCAM;n++) sv = fmaxf(sv, ac[n]);
  sv += ld1<F>(bv,t);

  sm.fus[t] = fmaxf(qv+sv, 0.f) + qv;
  __syncthreads();

  // phase 6: output projection
  float o = 0.f;
  {
    const f4* sf4=(const f4*)sm.fus;
    #pragma unroll 8
    for(int k4=0;k4<NC/4;k4++){
      f4 wv = RL ? Wo4[k4*256 + t] : ld4<F>(Wo, (long)t*NC + 4*k4);
      f4 xv = sf4[k4];
      o=fmaf(wv.x,xv.x,o); o=fmaf(wv.y,xv.y,o);
      o=fmaf(wv.z,xv.z,o); o=fmaf(wv.w,xv.w,o);
    }
    o += ld1<F>(bo,t);
  }
  if (m) o = 0.f;
  out[(long)row*NC+t] = o;
}

template<int RL, int RF>
__global__ __launch_bounds__(256,4) void fused_kernel(
    const void* query, const void* refpts, const void* intr,
    const void* f0, const void* f1, const void* f2, const void* f3,
    const void* Wq, const void* bq, const void* Wv, const void* bv,
    const void* Wo, const void* bo, const float* __restrict__ Wblk,
    const float* __restrict__ T2buf, const float* __restrict__ T3buf,
    const float* __restrict__ inv_ext, const int* __restrict__ mask_int,
    const int* __restrict__ flag, float* __restrict__ out){
  __shared__ SharedMem sm;
  if (*flag)
    fused_body<1,RL,RF>(query,refpts,intr,f0,f1,f2,f3,Wq,bq,Wv,bv,Wo,bo,
                        Wblk,T2buf,T3buf,inv_ext,mask_int,out,sm);
  else
    fused_body<0,RL,RF>(query,refpts,intr,f0,f1,f2,f3,Wq,bq,Wv,bv,Wo,bo,
                        Wblk,T2buf,T3buf,inv_ext,mask_int,out,sm);
}

extern "C" void kernel_launch(void* const* d_in, const int* in_sizes, int n_in,
                              void* d_out, int out_size, void* d_ws, size_t ws_size,
                              hipStream_t stream){
  const void* query  = d_in[0];
  const void* refpts = d_in[1];
  const unsigned char* mask_raw = (const unsigned char*)d_in[2];
  const void* intr   = d_in[3];
  const void* ext    = d_in[4];
  const void* f0     = d_in[5];
  const void* f1     = d_in[6];
  const void* f2     = d_in[7];
  const void* f3     = d_in[8];
  const void* Wq     = d_in[9];
  const void* bq     = d_in[10];
  const void* Wv     = d_in[11];
  const void* bv     = d_in[12];
  const void* Wo     = d_in[13];
  const void* bo     = d_in[14];

  char* ws = (char*)d_ws;
  float* inv_ext  = (float*)(ws + 0);         // 768 B
  int*   dflag    = (int*)  (ws + 1024);      // 4 B
  int*   mask_int = (int*)  (ws + 2048);      // 7200 B
  float* Wblk     = (float*)(ws + 16384);     // 786432 B
  float* T3buf    = (float*)(ws + 802816);    // 12*350*256*4  = 4300800 B
  float* T2buf    = (float*)(ws + 5103616);   // 12*1400*256*4 = 17203200 B
                                              // end: 22306816 B

  const size_t needW  = 802816;
  const size_t need3  = 5103616;
  const size_t need23 = 22306816;

  int rl = (ws_size >= needW) ? 1 : 0;
  int rf = (ws_size >= need23) ? 2 : ((ws_size >= need3) ? 1 : 0);

  int nW   = rl ? 768 : 0;
  int nT2t = (rf>=2) ? BN*TILES2 : 0;   // 4224
  int nT3t = (rf>=1) ? BN*TILES3 : 0;   // 1056

  hipLaunchKernelGGL(prep_all, dim3(nW+nT2t+nT3t+1), dim3(256), 0, stream,
                     (const unsigned char*)refpts, ext, mask_raw,
                     Wq, Wv, Wo, f2, f3, nW, nT2t, nT3t,
                     dflag, inv_ext, mask_int, Wblk, T2buf, T3buf);

  dim3 grid(NROW);
  if (rl && rf==2)
    hipLaunchKernelGGL(HIP_KERNEL_NAME(fused_kernel<1,2>), grid, dim3(256), 0, stream,
                       query, refpts, intr, f0, f1, f2, f3,
                       Wq, bq, Wv, bv, Wo, bo, Wblk, T2buf, T3buf,
                       inv_ext, mask_int, dflag, (float*)d_out);
  else if (rl && rf==1)
    hipLaunchKernelGGL(HIP_KERNEL_NAME(fused_kernel<1,1>), grid, dim3(256), 0, stream,
                       query, refpts, intr, f0, f1, f2, f3,
                       Wq, bq, Wv, bv, Wo, bo, Wblk, T2buf, T3buf,
                       inv_ext, mask_int, dflag, (float*)d_out);
  else if (rl)
    hipLaunchKernelGGL(HIP_KERNEL_NAME(fused_kernel<1,0>), grid, dim3(256), 0, stream,
                       query, refpts, intr, f0, f1, f2, f3,
                       Wq, bq, Wv, bv, Wo, bo, Wblk, T2buf, T3buf,
                       inv_ext, mask_int, dflag, (float*)d_out);
  else
    hipLaunchKernelGGL(HIP_KERNEL_NAME(fused_kernel<0,0>), grid, dim3(256), 0, stream,
                       query, refpts, intr, f0, f1, f2, f3,
                       Wq, bq, Wv, bv, Wo, bo, Wblk, T2buf, T3buf,
                       inv_ext, mask_int, dflag, (float*)d_out);
}

// Round 3
// 494.278 us; speedup vs baseline: 1.0975x; 1.0182x over previous
//
#include <hip/hip_runtime.h>
#include <hip/hip_bf16.h>
#include <math.h>

#define BB 2
#define NCAM 6
#define NQ 900
#define NC 256
#define BN (BB*NCAM)        // 12
#define NROW (BB*NQ)        // 1800
#define RPB 2               // rows (queries) per block

#define HW0 22400
#define HW1 5600
#define HW2 1400
#define HW3 350

typedef float f4 __attribute__((ext_vector_type(4)));
typedef unsigned short u16x4 __attribute__((ext_vector_type(4)));
typedef struct __attribute__((aligned(4))) { float x, y; } pf2;   // 4B-aligned float pair

__device__ __forceinline__ float u2f(unsigned short u){
  union{unsigned int v; float fl;} x; x.v=((unsigned int)u)<<16; return x.fl;
}

template<int F>
__device__ __forceinline__ float ld1(const void* p, long i){
  if (F) return u2f(((const unsigned short*)p)[i]);
  return ((const float*)p)[i];
}
template<int F>
__device__ __forceinline__ f4 ld4(const void* p, long i){ // i = element index, %4==0
  if (F){
    u16x4 u = *(const u16x4*)((const unsigned short*)p + i);
    f4 r; r.x=u2f(u.x); r.y=u2f(u.y); r.z=u2f(u.z); r.w=u2f(u.w); return r;
  }
  return *(const f4*)((const float*)p + i);
}

// 4 bilinear corner values via 2 paired loads (fp32) or 4 scalar loads (bf16).
// offA/offB are row bases (cy0*W+px, cy1*W+px) with px=clamp(x0,0,W-2);
// d0/d1 in {0,1} select the clip-index within the pair.
template<int F>
__device__ __forceinline__ void corner4(const void* fp, long cb, int offA, int offB,
                                        int d0, int d1, float* v){
  if (F){
    v[0]=ld1<1>(fp,cb+offA+d0); v[1]=ld1<1>(fp,cb+offA+d1);
    v[2]=ld1<1>(fp,cb+offB+d0); v[3]=ld1<1>(fp,cb+offB+d1);
  } else {
    pf2 a = *(const pf2*)((const float*)fp + cb + offA);
    pf2 b = *(const pf2*)((const float*)fp + cb + offB);
    v[0]=d0?a.y:a.x; v[1]=d1?a.y:a.x;
    v[2]=d0?b.y:b.x; v[3]=d1?b.y:b.x;
  }
}

__device__ __forceinline__ int sniff_flag(const unsigned char* refraw){
  int cnt=0;
  for (int i=1;i<64;i+=4){
    unsigned char b = refraw[i];
    if (b>=0x30 && b<0x40) cnt++;
  }
  return (cnt>=12) ? 1 : 0;
}

// ---------------- combined prep kernel ----------------
#define TILES2 (8*44)     // per-bn tiles for HW2=1400 (44 p-tiles x 8 c-tiles)
#define TILES3 (8*11)     // per-bn tiles for HW3=350
__global__ __launch_bounds__(256) void prep_all(
    const unsigned char* __restrict__ refraw,
    const void* __restrict__ ext,
    const unsigned char* __restrict__ mask_raw,
    const void* __restrict__ Wq, const void* __restrict__ Wv,
    const void* __restrict__ Wo,
    const void* __restrict__ f2, const void* __restrict__ f3,
    int nW, int nT2t, int nT3t,
    int* __restrict__ flag_out, float* __restrict__ inv_out,
    int* __restrict__ mask_out,
    float* __restrict__ Wblk, float* __restrict__ T2buf,
    float* __restrict__ T3buf){
  __shared__ int sflag, s_na, s_gt, s_bf;
  __shared__ float tile[32][33];
  int t = threadIdx.x;
  int bi = blockIdx.x;
  if (t==0){ sflag = sniff_flag(refraw); s_na=0; s_gt=0; s_bf=0; }
  __syncthreads();
  int f = sflag;

  if (bi < nW){
    int e = bi*256 + t;                 // 0 .. 3*65536-1
    int mat = e >> 16;
    int i = e & 65535;
    int tt = i >> 8, k = i & 255;
    const void* W = (mat==0)?Wq:((mat==1)?Wv:Wo);
    float v = f ? u2f(((const unsigned short*)W)[i]) : ((const float*)W)[i];
    Wblk[mat*65536 + (k>>2)*1024 + tt*4 + (k&3)] = v;
    return;
  }
  if (bi < nW+nT2t+nT3t){
    // LDS-tiled transpose: both global sides coalesced.
    int idx = bi - nW;
    const void* src; float* dst; int HW, tpb, tp;
    if (idx < nT2t){ HW=HW2; src=f2; dst=T2buf; tpb=TILES2; tp=44; }
    else { idx -= nT2t; HW=HW3; src=f3; dst=T3buf; tpb=TILES3; tp=11; }
    int bn = idx / tpb; int rem = idx - bn*tpb;
    int ct = rem / tp,  pt = rem - ct*tp;
    int c0 = ct*32, p0 = pt*32;
    int ty = t>>5, tx = t&31;
    #pragma unroll
    for (int r=0;r<4;r++){
      int c = c0 + ty + r*8;          // < 256 always
      int p = p0 + tx;
      float v = 0.f;
      if (p < HW){
        long s = (long)(bn*NC + c)*HW + p;
        v = f ? u2f(((const unsigned short*)src)[s]) : ((const float*)src)[s];
      }
      tile[ty+r*8][tx] = v;
    }
    __syncthreads();
    #pragma unroll
    for (int r=0;r<4;r++){
      int p = p0 + ty + r*8;
      if (p < HW)
        dst[((long)bn*HW + p)*NC + c0 + tx] = tile[tx][ty+r*8];
    }
    return;
  }

  // ---- prep block ----
  int f_na=0, f_gt=0, f_bf=0;
  for (int i=t;i<NROW;i+=blockDim.x){
    unsigned char b = mask_raw[i];
    if ((i&3)!=0 && b!=0) f_na=1;
    if (b>1) f_gt=1;
    if ((i&3)==1 && b==0x3f) f_bf=1;
  }
  if (f_na) atomicOr(&s_na,1);
  if (f_gt) atomicOr(&s_gt,1);
  if (f_bf) atomicOr(&s_bf,1);
  __syncthreads();
  int fmt; // 0=int32, 1=uint8(bool), 2=bf16, 3=fp32
  if (!s_na) fmt=0;
  else if (!s_gt) fmt=1;
  else fmt = s_bf ? 2 : 3;
  for (int i=t;i<NROW;i+=blockDim.x){
    int v;
    if (fmt==0)      v = (((const int*)mask_raw)[i]            != 0);
    else if (fmt==1) v = (mask_raw[i]                          != 0);
    else if (fmt==2) v = (((const unsigned short*)mask_raw)[i] != 0);
    else             v = (((const float*)mask_raw)[i]          != 0.0f);
    mask_out[i]=v;
  }
  if (t==0) *flag_out = f;
  if (t < BN){
    double a[4][8];
    for(int i=0;i<4;i++){
      for(int j=0;j<4;j++) a[i][j] = (double)(f? u2f(((const unsigned short*)ext)[t*16+i*4+j])
                                               : ((const float*)ext)[t*16+i*4+j]);
      for(int j=0;j<4;j++) a[i][4+j] = (i==j)?1.0:0.0;
    }
    for(int col=0;col<4;col++){
      int piv=col; double best=fabs(a[col][col]);
      for(int r=col+1;r<4;r++){ double v=fabs(a[r][col]); if(v>best){best=v;piv=r;} }
      if(piv!=col) for(int j=0;j<8;j++){ double tmp=a[col][j]; a[col][j]=a[piv][j]; a[piv][j]=tmp; }
      double id = 1.0/a[col][col];
      for(int j=0;j<8;j++) a[col][j]*=id;
      for(int r=0;r<4;r++) if(r!=col){
        double fc=a[r][col];
        for(int j=0;j<8;j++) a[r][j]-=fc*a[col][j];
      }
    }
    for(int i=0;i<4;i++)for(int j=0;j<4;j++){
      float v=(float)a[i][4+j];
      if (isnan(v)) v=0.f;
      else if (isinf(v)) v = (v>0.f)?1e6f:-1e6f;
      inv_out[t*16+i*4+j]=v;
    }
  }
}

// ---------------- fused kernel, RPB rows per block ----------------
struct SharedMem {
  float q[RPB][NC];
  float ms[RPB][NCAM][NC];
  float fus[RPB][NC];
  float px[RPB][NCAM], py[RPB][NCAM];
  int   iv[RPB][NCAM];
  int   off[RPB][NCAM*4][4];   // [0]=offA, [1]=offB, [2]=d0, [3]=d1
  float wgt[RPB][NCAM*4][4];
};

// RL: weights from relaid fp32 blocked buffer. RF: 0 none, 1 l3 relaid, 2 l2+l3 relaid.
template<int F, int RL, int RF>
__device__ __forceinline__ void fused_body(
    const void* __restrict__ query, const void* __restrict__ refpts,
    const void* __restrict__ intr,
    const void* __restrict__ f0, const void* __restrict__ f1,
    const void* __restrict__ f2, const void* __restrict__ f3,
    const void* __restrict__ Wq, const void* __restrict__ bq,
    const void* __restrict__ Wv, const void* __restrict__ bv,
    const void* __restrict__ Wo, const void* __restrict__ bo,
    const float* __restrict__ Wblk,
    const float* __restrict__ T2buf, const float* __restrict__ T3buf,
    const float* __restrict__ inv_ext, const int* __restrict__ mask_int,
    float* __restrict__ out, SharedMem& sm){
  int r0 = blockIdx.x*RPB;
  int t = threadIdx.x;

  const f4* Wq4 = (const f4*)(Wblk);
  const f4* Wv4 = (const f4*)(Wblk + 65536);
  const f4* Wo4 = (const f4*)(Wblk + 131072);

  // phase 1: stage query rows; first RPB*NCAM threads project through cameras
  #pragma unroll
  for(int i=0;i<RPB;i++) sm.q[i][t] = ld1<F>(query,(long)(r0+i)*NC+t);

  if (t < RPB*NCAM){
    int i = t/NCAM, n = t - i*NCAM;
    int row = r0+i, b = row/NQ;
    int m = mask_int[row];
    float h0 = ld1<F>(refpts,(long)row*3+0)*102.4f - 51.2f;
    float h1 = ld1<F>(refpts,(long)row*3+1)*102.4f - 51.2f;
    float h2 = ld1<F>(refpts,(long)row*3+2)*102.4f - 51.2f;
    if (m){ h0=-1000.f; h1=-1000.f; h2=-1000.f; }
    const float* M = inv_ext + (b*NCAM+n)*16;
    float c0 = M[0]*h0 + M[1]*h1 + M[2]*h2 + M[3];
    float c1 = M[4]*h0 + M[5]*h1 + M[6]*h2 + M[7];
    float c2 = M[8]*h0 + M[9]*h1 + M[10]*h2 + M[11];
    float depth = c2;
    if (isnan(depth)) depth = 10.f;
    else if (isinf(depth)) depth = (depth>0)?100.f:-100.f;
    int iv = (depth < 1.5f);
    float ds = fmaxf(depth, 1.5f);
    float pc0=c0/ds, pc1=c1/ds, pc2=c2/ds;
    long kb = (long)(b*NCAM+n)*9;
    float ix = ld1<F>(intr,kb+0)*pc0 + ld1<F>(intr,kb+1)*pc1 + ld1<F>(intr,kb+2)*pc2;
    float iy = ld1<F>(intr,kb+3)*pc0 + ld1<F>(intr,kb+4)*pc1 + ld1<F>(intr,kb+5)*pc2;
    sm.px[i][n] = fminf(fmaxf(ix,-3000.f),3000.f);
    sm.py[i][n] = fminf(fmaxf(iy,-3000.f),3000.f);
    sm.iv[i][n] = iv;
  }
  __syncthreads();

  // phase 2: per (row,cam,level) pair bases + selects + weights
  if (t < RPB*NCAM*4){
    const int Ws_[4]={200,100,50,25}, Hs_[4]={112,56,28,14};
    int i = t/(NCAM*4), u = t - i*(NCAM*4);
    int n = u>>2, l = u&3;
    float x=sm.px[i][n], y=sm.py[i][n];
    int iv=sm.iv[i][n];
    int W=Ws_[l], H=Hs_[l];
    float gx = (x * ((float)W/800.f)) / (W-1.f) * 2.f - 1.f;
    float gy = (y * ((float)H/448.f)) / (H-1.f) * 2.f - 1.f;
    gx=fminf(fmaxf(gx,-10.f),10.f); gy=fminf(fmaxf(gy,-10.f),10.f);
    if(iv){gx=-100.f;gy=-100.f;}
    float pxx=(gx+1.f)*0.5f*(W-1.f);
    float pyy=(gy+1.f)*0.5f*(H-1.f);
    float x0f=floorf(pxx), y0f=floorf(pyy);
    int x0=(int)x0f, y0=(int)y0f;
    float wx1=pxx-x0f, wy1=pyy-y0f, wx0=1.f-wx1, wy0=1.f-wy1;
    int vx0=(x0>=0)&(x0<W), vx1=(x0+1>=0)&(x0+1<W);
    int vy0=(y0>=0)&(y0<H), vy1=(y0+1>=0)&(y0+1<H);
    int cx0=min(max(x0,0),W-1), cx1=min(max(x0+1,0),W-1);
    int cy0=min(max(y0,0),H-1), cy1=min(max(y0+1,0),H-1);
    int px = min(max(x0,0),W-2);         // pair base column
    int d0 = cx0 - px, d1 = cx1 - px;    // in {0,1}
    sm.off[i][u][0]=cy0*W+px; sm.off[i][u][1]=cy1*W+px;
    sm.off[i][u][2]=d0;       sm.off[i][u][3]=d1;
    sm.wgt[i][u][0]=wx0*wy0*(float)(vx0&vy0);
    sm.wgt[i][u][1]=wx1*wy0*(float)(vx1&vy0);
    sm.wgt[i][u][2]=wx0*wy1*(float)(vx0&vy1);
    sm.wgt[i][u][3]=wx1*wy1*(float)(vx1&vy1);
  }
  __syncthreads();

  // phase 3: sampling — thread t = channel t; paired gathers for l0/l1,
  // coalesced channel-last loads for l2/l3. Both rows interleaved per cam.
  {
    #pragma unroll
    for(int n=0;n<NCAM;n++){
      #pragma unroll
      for(int i=0;i<RPB;i++){
        int b = (r0+i)/NQ;
        int bn = b*NCAM+n;
        int chan = bn*NC + t;
        float v[16];
        corner4<F>(f0, (long)chan*HW0,
                   sm.off[i][n*4+0][0], sm.off[i][n*4+0][1],
                   sm.off[i][n*4+0][2], sm.off[i][n*4+0][3], &v[0]);
        corner4<F>(f1, (long)chan*HW1,
                   sm.off[i][n*4+1][0], sm.off[i][n*4+1][1],
                   sm.off[i][n*4+1][2], sm.off[i][n*4+1][3], &v[4]);
        {
          int u=n*4+2;
          if (RF>=2){
            const float* Tp = T2buf + (long)bn*(HW2*NC) + t;
            int oA=sm.off[i][u][0], oB=sm.off[i][u][1], d0=sm.off[i][u][2], d1=sm.off[i][u][3];
            v[8] =Tp[(long)(oA+d0)*NC]; v[9] =Tp[(long)(oA+d1)*NC];
            v[10]=Tp[(long)(oB+d0)*NC]; v[11]=Tp[(long)(oB+d1)*NC];
          } else {
            corner4<F>(f2, (long)chan*HW2,
                       sm.off[i][u][0], sm.off[i][u][1],
                       sm.off[i][u][2], sm.off[i][u][3], &v[8]);
          }
        }
        {
          int u=n*4+3;
          if (RF>=1){
            const float* Tp = T3buf + (long)bn*(HW3*NC) + t;
            int oA=sm.off[i][u][0], oB=sm.off[i][u][1], d0=sm.off[i][u][2], d1=sm.off[i][u][3];
            v[12]=Tp[(long)(oA+d0)*NC]; v[13]=Tp[(long)(oA+d1)*NC];
            v[14]=Tp[(long)(oB+d0)*NC]; v[15]=Tp[(long)(oB+d1)*NC];
          } else {
            corner4<F>(f3, (long)chan*HW3,
                       sm.off[i][u][0], sm.off[i][u][1],
                       sm.off[i][u][2], sm.off[i][u][3], &v[12]);
          }
        }
        float acc=0.f;
        #pragma unroll
        for(int l=0;l<4;l++){
          #pragma unroll
          for(int c=0;c<4;c++)
            acc = fmaf(sm.wgt[i][n*4+l][c], v[l*4+c], acc);
        }
        sm.ms[i][n][t]=acc*0.25f;
      }
    }
  }

  // phase 4: q projection (row t of Wq), weight loaded once for RPB rows
  float qv[RPB];
  #pragma unroll
  for(int i=0;i<RPB;i++) qv[i]=0.f;
  {
    #pragma unroll 8
    for(int k4=0;k4<NC/4;k4++){
      f4 wv = RL ? Wq4[k4*256 + t] : ld4<F>(Wq, (long)t*NC + 4*k4);
      #pragma unroll
      for(int i=0;i<RPB;i++){
        f4 xv = ((const f4*)sm.q[i])[k4];
        qv[i]=fmaf(wv.x,xv.x,qv[i]); qv[i]=fmaf(wv.y,xv.y,qv[i]);
        qv[i]=fmaf(wv.z,xv.z,qv[i]); qv[i]=fmaf(wv.w,xv.w,qv[i]);
      }
    }
    float bqv = ld1<F>(bq,t);
    #pragma unroll
    for(int i=0;i<RPB;i++) qv[i]+=bqv;
  }
  __syncthreads();   // sm.ms ready

  // phase 5: v projection + max over cameras, weight loaded once for RPB rows
  float ac[RPB][NCAM];
  #pragma unroll
  for(int i=0;i<RPB;i++)
    #pragma unroll
    for(int n=0;n<NCAM;n++) ac[i][n]=0.f;
  {
    #pragma unroll 2
    for(int k4=0;k4<NC/4;k4++){
      f4 wv = RL ? Wv4[k4*256 + t] : ld4<F>(Wv, (long)t*NC + 4*k4);
      #pragma unroll
      for(int i=0;i<RPB;i++){
        #pragma unroll
        for(int n=0;n<NCAM;n++){
          f4 mv=((const f4*)sm.ms[i][n])[k4];
          ac[i][n]=fmaf(wv.x,mv.x,ac[i][n]); ac[i][n]=fmaf(wv.y,mv.y,ac[i][n]);
          ac[i][n]=fmaf(wv.z,mv.z,ac[i][n]); ac[i][n]=fmaf(wv.w,mv.w,ac[i][n]);
        }
      }
    }
  }
  {
    float bvv = ld1<F>(bv,t);
    #pragma unroll
    for(int i=0;i<RPB;i++){
      float sv = ac[i][0];
      #pragma unroll
      for(int n=1;n<NCAM;n++) sv = fmaxf(sv, ac[i][n]);
      sv += bvv;
      sm.fus[i][t] = fmaxf(qv[i]+sv, 0.f) + qv[i];
    }
  }
  __syncthreads();

  // phase 6: output projection
  float o[RPB];
  #pragma unroll
  for(int i=0;i<RPB;i++) o[i]=0.f;
  {
    #pragma unroll 8
    for(int k4=0;k4<NC/4;k4++){
      f4 wv = RL ? Wo4[k4*256 + t] : ld4<F>(Wo, (long)t*NC + 4*k4);
      #pragma unroll
      for(int i=0;i<RPB;i++){
        f4 xv = ((const f4*)sm.fus[i])[k4];
        o[i]=fmaf(wv.x,xv.x,o[i]); o[i]=fmaf(wv.y,xv.y,o[i]);
        o[i]=fmaf(wv.z,xv.z,o[i]); o[i]=fmaf(wv.w,xv.w,o[i]);
      }
    }
    float bov = ld1<F>(bo,t);
    #pragma unroll
    for(int i=0;i<RPB;i++){
      int m = mask_int[r0+i];
      float r = o[i] + bov;
      if (m) r = 0.f;
      out[(long)(r0+i)*NC+t] = r;
    }
  }
}

template<int RL, int RF>
__global__ __launch_bounds__(256,4) void fused_kernel(
    const void* query, const void* refpts, const void* intr,
    const void* f0, const void* f1, const void* f2, const void* f3,
    const void* Wq, const void* bq, const void* Wv, const void* bv,
    const void* Wo, const void* bo, const float* __restrict__ Wblk,
    const float* __restrict__ T2buf, const float* __restrict__ T3buf,
    const float* __restrict__ inv_ext, const int* __restrict__ mask_int,
    const int* __restrict__ flag, float* __restrict__ out){
  __shared__ SharedMem sm;
  if (*flag)
    fused_body<1,RL,RF>(query,refpts,intr,f0,f1,f2,f3,Wq,bq,Wv,bv,Wo,bo,
                        Wblk,T2buf,T3buf,inv_ext,mask_int,out,sm);
  else
    fused_body<0,RL,RF>(query,refpts,intr,f0,f1,f2,f3,Wq,bq,Wv,bv,Wo,bo,
                        Wblk,T2buf,T3buf,inv_ext,mask_int,out,sm);
}

extern "C" void kernel_launch(void* const* d_in, const int* in_sizes, int n_in,
                              void* d_out, int out_size, void* d_ws, size_t ws_size,
                              hipStream_t stream){
  const void* query  = d_in[0];
  const void* refpts = d_in[1];
  const unsigned char* mask_raw = (const unsigned char*)d_in[2];
  const void* intr   = d_in[3];
  const void* ext    = d_in[4];
  const void* f0     = d_in[5];
  const void* f1     = d_in[6];
  const void* f2     = d_in[7];
  const void* f3     = d_in[8];
  const void* Wq     = d_in[9];
  const void* bq     = d_in[10];
  const void* Wv     = d_in[11];
  const void* bv     = d_in[12];
  const void* Wo     = d_in[13];
  const void* bo     = d_in[14];

  char* ws = (char*)d_ws;
  float* inv_ext  = (float*)(ws + 0);         // 768 B
  int*   dflag    = (int*)  (ws + 1024);      // 4 B
  int*   mask_int = (int*)  (ws + 2048);      // 7200 B
  float* Wblk     = (float*)(ws + 16384);     // 786432 B
  float* T3buf    = (float*)(ws + 802816);    // 12*350*256*4  = 4300800 B
  float* T2buf    = (float*)(ws + 5103616);   // 12*1400*256*4 = 17203200 B
                                              // end: 22306816 B

  const size_t needW  = 802816;
  const size_t need3  = 5103616;
  const size_t need23 = 22306816;

  int rl = (ws_size >= needW) ? 1 : 0;
  int rf = (ws_size >= need23) ? 2 : ((ws_size >= need3) ? 1 : 0);

  int nW   = rl ? 768 : 0;
  int nT2t = (rf>=2) ? BN*TILES2 : 0;   // 4224
  int nT3t = (rf>=1) ? BN*TILES3 : 0;   // 1056

  hipLaunchKernelGGL(prep_all, dim3(nW+nT2t+nT3t+1), dim3(256), 0, stream,
                     (const unsigned char*)refpts, ext, mask_raw,
                     Wq, Wv, Wo, f2, f3, nW, nT2t, nT3t,
                     dflag, inv_ext, mask_int, Wblk, T2buf, T3buf);

  dim3 grid(NROW/RPB);
  if (rl && rf==2)
    hipLaunchKernelGGL(HIP_KERNEL_NAME(fused_kernel<1,2>), grid, dim3(256), 0, stream,
                       query, refpts, intr, f0, f1, f2, f3,
                       Wq, bq, Wv, bv, Wo, bo, Wblk, T2buf, T3buf,
                       inv_ext, mask_int, dflag, (float*)d_out);
  else if (rl && rf==1)
    hipLaunchKernelGGL(HIP_KERNEL_NAME(fused_kernel<1,1>), grid, dim3(256), 0, stream,
                       query, refpts, intr, f0, f1, f2, f3,
                       Wq, bq, Wv, bv, Wo, bo, Wblk, T2buf, T3buf,
                       inv_ext, mask_int, dflag, (float*)d_out);
  else if (rl)
    hipLaunchKernelGGL(HIP_KERNEL_NAME(fused_kernel<1,0>), grid, dim3(256), 0, stream,
                       query, refpts, intr, f0, f1, f2, f3,
                       Wq, bq, Wv, bv, Wo, bo, Wblk, T2buf, T3buf,
                       inv_ext, mask_int, dflag, (float*)d_out);
  else
    hipLaunchKernelGGL(HIP_KERNEL_NAME(fused_kernel<0,0>), grid, dim3(256), 0, stream,
                       query, refpts, intr, f0, f1, f2, f3,
                       Wq, bq, Wv, bv, Wo, bo, Wblk, T2buf, T3buf,
                       inv_ext, mask_int, dflag, (float*)d_out);
}